// Round 13
// baseline (213.503 us; speedup 1.0000x reference)
//
#include <hip/hip_runtime.h>

#define T_TEST 8192
#define BB 8
#define FF 100
#define HH 512

typedef __bf16 bf16x8 __attribute__((ext_vector_type(8)));
typedef float f32x16 __attribute__((ext_vector_type(16)));
typedef unsigned short u16;
typedef unsigned int u32;

__device__ __forceinline__ u16 f2bf(float f) {
    u32 u = __float_as_uint(f);
    u += 0x7fffu + ((u >> 16) & 1);   // RNE
    return (u16)(u >> 16);
}

__device__ __forceinline__ float nan2num(float v) {
    u32 u = __float_as_uint(v);
    if ((u & 0x7f800000u) == 0x7f800000u) {
        v = (u & 0x007fffffu) ? 0.f : ((u >> 31) ? -3.3895314e38f : 3.3895314e38f);
    }
    return v;
}

// ---- weight prep: 32x32x16 fragment-major (unchanged layouts) ----------
// B-frag: B[k][n], n = lane&31, k = (lane>>5)*8 + j, 8 bf16/lane.
// w1f frag idx: ((b*8  + ks)*16 + n32)*64 + lane
// w2f frag idx: ((b*32 + ks)*16 + n32)*64 + lane
__global__ void prep_w(const float* __restrict__ w1, const float* __restrict__ w2,
                       u16* __restrict__ w1f, u16* __restrict__ w2f) {
    int bid = blockIdx.x;
    if (bid < 256) {                      // w1f
        int t = bid * 256 + threadIdx.x;
        int lane = t & 63;
        int n32 = (t >> 6) & 15;
        int b = t >> 13;
        int n = n32 * 32 + (lane & 31);
        int kb = ((t >> 10) & 7) * 16 + (lane >> 5) * 8;
        u32 p[4];
#pragma unroll
        for (int jp = 0; jp < 4; ++jp) {
            int k0 = kb + jp * 2;
            float v0 = (k0 < FF)     ? w1[(b * FF + k0) * HH + n]     : 0.f;
            float v1 = (k0 + 1 < FF) ? w1[(b * FF + k0 + 1) * HH + n] : 0.f;
            p[jp] = (u32)f2bf(v0) | ((u32)f2bf(v1) << 16);
        }
        uint4 o = {p[0], p[1], p[2], p[3]};
        *(uint4*)(w1f + (size_t)t * 8) = o;
    } else {                              // w2f
        int t = (bid - 256) * 256 + threadIdx.x;
        int lane = t & 63;
        int n32 = (t >> 6) & 15;
        int b = t >> 15;
        int n = n32 * 32 + (lane & 31);
        int kb = ((t >> 10) & 31) * 16 + (lane >> 5) * 8;
        u32 p[4];
#pragma unroll
        for (int jp = 0; jp < 4; ++jp) {
            int k0 = kb + jp * 2;
            float v0 = w2[(b * HH + k0) * HH + n];
            float v1 = w2[(b * HH + k0 + 1) * HH + n];
            p[jp] = (u32)f2bf(v0) | ((u32)f2bf(v1) << 16);
        }
        uint4 o = {p[0], p[1], p[2], p[3]};
        *(uint4*)(w2f + (size_t)t * 8) = o;
    }
}

// out[t*8+b] = b3[b]  (l23 accumulates onto this with atomics)
__global__ void init_out(const float* __restrict__ b3, float* __restrict__ out) {
    int i = blockIdx.x * 256 + threadIdx.x;
    out[i] = b3[i & 7];
}

// ---- kernel A: layer 1 -> h1g (global, frag-major per 64-row tile) -----
// h1g tile layout: fi = ks*2+mi in [0,32), 1 KB frags; tile = 64 KB.
__global__ __launch_bounds__(512, 2) void l1_kernel(
    const float* __restrict__ x, const u16* __restrict__ w1f,
    const float* __restrict__ b1, u16* __restrict__ h1g) {
    __shared__ __align__(16) char lds[81920];
    u16* xf  = (u16*)lds;                  // x frags, 16 KB
    u16* h1f = (u16*)(lds + 16384);        // h1 frags, 64 KB

    const int tid = threadIdx.x;
    const int b = blockIdx.x;
    const int m0 = blockIdx.y * 64;
    const int lane = tid & 63;
    const int ws = __builtin_amdgcn_readfirstlane(tid >> 6);
    const int l31 = lane & 31, lh = lane >> 5;
    const int n32b = ws * 2;

    const bf16x8* W1 = (const bf16x8*)w1f + (size_t)b * 8192;

    bf16x8 pa[2][2], pb[4][2];

#pragma unroll
    for (int s = 0; s < 4; ++s)
#pragma unroll
        for (int ni = 0; ni < 2; ++ni)
            pb[s][ni] = W1[(s * 16 + n32b + ni) * 64 + lane];

    float b1v[2];
    b1v[0] = b1[b * HH + (n32b + 0) * 32 + l31];
    b1v[1] = b1[b * HH + (n32b + 1) * 32 + l31];

    if (ws < 7) {
        int row = lane, s = ws;
        int mi = row >> 5, m = row & 31;
        const float* xr = x + ((size_t)(m0 + row) * BB + b) * FF + s * 16;
        u32 p[8];
#pragma unroll
        for (int i = 0; i < 8; ++i) p[i] = 0;
        if (s <= 5) {
#pragma unroll
            for (int j = 0; j < 4; ++j) {
                float4 v = *(const float4*)(xr + j * 4);
                p[j * 2 + 0] = (u32)f2bf(nan2num(v.x)) | ((u32)f2bf(nan2num(v.y)) << 16);
                p[j * 2 + 1] = (u32)f2bf(nan2num(v.z)) | ((u32)f2bf(nan2num(v.w)) << 16);
            }
        } else {
            float4 v = *(const float4*)(xr);
            p[0] = (u32)f2bf(nan2num(v.x)) | ((u32)f2bf(nan2num(v.y)) << 16);
            p[1] = (u32)f2bf(nan2num(v.z)) | ((u32)f2bf(nan2num(v.w)) << 16);
        }
        int fi1 = s * 2 + mi;
        uint4 g0 = {p[0], p[1], p[2], p[3]};
        uint4 g1 = {p[4], p[5], p[6], p[7]};
        *(uint4*)(xf + (fi1 * 64 + m) * 8)      = g0;
        *(uint4*)(xf + (fi1 * 64 + 32 + m) * 8) = g1;
    }
    __syncthreads();

    f32x16 acc1[2][2] = {};
#pragma unroll
    for (int s = 0; s < 2; ++s)
#pragma unroll
        for (int mi = 0; mi < 2; ++mi)
            pa[s][mi] = *(const bf16x8*)(xf + ((s * 2 + mi) * 64 + lane) * 8);
#pragma unroll
    for (int ks = 0; ks < 7; ++ks) {
        const int pA = ks & 1, pB = ks & 3;
        bf16x8 a0 = pa[pA][0], a1 = pa[pA][1];
        bf16x8 b0 = pb[pB][0], b1r = pb[pB][1];
        if (ks < 5) {
#pragma unroll
            for (int mi = 0; mi < 2; ++mi)
                pa[pA][mi] = *(const bf16x8*)(xf + (((ks + 2) * 2 + mi) * 64 + lane) * 8);
        }
        if (ks < 3) {
#pragma unroll
            for (int ni = 0; ni < 2; ++ni)
                pb[pB][ni] = W1[((ks + 4) * 16 + n32b + ni) * 64 + lane];
        }
        acc1[0][0] = __builtin_amdgcn_mfma_f32_32x32x16_bf16(a0, b0,  acc1[0][0], 0, 0, 0);
        acc1[0][1] = __builtin_amdgcn_mfma_f32_32x32x16_bf16(a0, b1r, acc1[0][1], 0, 0, 0);
        acc1[1][0] = __builtin_amdgcn_mfma_f32_32x32x16_bf16(a1, b0,  acc1[1][0], 0, 0, 0);
        acc1[1][1] = __builtin_amdgcn_mfma_f32_32x32x16_bf16(a1, b1r, acc1[1][1], 0, 0, 0);
    }

    // epilogue: relu(acc1+b1) -> h1f in A-frag order
    {
        char* hw = (char*)h1f + (l31 >> 4) * 2048 + ((l31 >> 3) & 1) * 512 +
                   (l31 & 6) * 2 + lh * 64 + n32b * 4096;
#pragma unroll
        for (int ni = 0; ni < 2; ++ni) {
#pragma unroll
            for (int mi = 0; mi < 2; ++mi)
#pragma unroll
                for (int qd = 0; qd < 4; ++qd) {
                    u32 own01 = (u32)f2bf(fmaxf(acc1[mi][ni][qd * 4 + 0] + b1v[ni], 0.f)) |
                                ((u32)f2bf(fmaxf(acc1[mi][ni][qd * 4 + 1] + b1v[ni], 0.f)) << 16);
                    u32 own23 = (u32)f2bf(fmaxf(acc1[mi][ni][qd * 4 + 2] + b1v[ni], 0.f)) |
                                ((u32)f2bf(fmaxf(acc1[mi][ni][qd * 4 + 3] + b1v[ni], 0.f)) << 16);
                    u32 oth01 = __shfl_xor(own01, 1, 64);
                    u32 oth23 = __shfl_xor(own23, 1, 64);
                    char* base = hw + ni * 4096 + mi * 1024 + qd * 128;
                    if (!(lane & 1)) {
                        *(u32*)(base +  0) = (own01 & 0xffffu) | (oth01 << 16);
                        *(u32*)(base + 16) = (own01 >> 16) | (oth01 & 0xffff0000u);
                    } else {
                        *(u32*)(base + 32) = (oth23 & 0xffffu) | (own23 << 16);
                        *(u32*)(base + 48) = (oth23 >> 16) | (own23 & 0xffff0000u);
                    }
                }
        }
    }
    __syncthreads();

    // coalesced copy-out: 64 KB tile -> h1g
    {
        const uint4* src = (const uint4*)h1f;
        uint4* dst = (uint4*)(h1g + (size_t)(b * 128 + blockIdx.y) * 32768);
#pragma unroll
        for (int j = 0; j < 8; ++j)
            dst[tid + j * 512] = src[tid + j * 512];
    }
}

// ---- kernel B v2: layer 2+3, B-slice in LDS, A streamed from global ----
// block = (b, nsl: 2 n32 cols) x 1024 rows; 8 waves x 4 rowtiles(32) each.
// grid: x = b*8+rg (so all 8 nsl of (b,rg) share an XCD), y = nsl.
__global__ __launch_bounds__(512, 4) void l23_kernel(
    const u16* __restrict__ h1g, const u16* __restrict__ w2f,
    const float* __restrict__ b2, const float* __restrict__ w3,
    float* __restrict__ out) {
    __shared__ __align__(16) char ldsB[65536];   // w2 slice: fk = ks*2+ni, 1 KB frags

    const int tid = threadIdx.x;
    const int bx = blockIdx.x;             // b*8 + rg
    const int b = bx >> 3, rg = bx & 7;
    const int nsl = blockIdx.y;            // 0..7
    const int lane = tid & 63;
    const int ws = __builtin_amdgcn_readfirstlane(tid >> 6);
    const int l31 = lane & 31, lh = lane >> 5;
    const int n32b = nsl * 2;

    // ---- stage w2 slice (64 KB) into LDS, once ----
    {
        const char* W2b = (const char*)w2f + (size_t)b * 524288;  // 32768 frags*16B
#pragma unroll
        for (int j = 0; j < 8; ++j) {
            int g = j * 512 + tid;          // vec4 index 0..4095
            int f = g >> 6, l = g & 63;     // f = ks*2+ni
            int ks = f >> 1, ni = f & 1;
            int srcfrag = (ks * 16 + n32b + ni) * 64 + l;
            *(uint4*)(ldsB + (size_t)g * 16) =
                *(const uint4*)(W2b + (size_t)srcfrag * 16);
        }
    }

    // layer-3 coefficients
    float b2v[2], w3v[2];
#pragma unroll
    for (int ni = 0; ni < 2; ++ni) {
        int n = (n32b + ni) * 32 + l31;
        b2v[ni] = b2[b * HH + n];
        w3v[ni] = w3[b * HH + n];
    }
    __syncthreads();                       // the only barrier

    // ---- 4 rowtiles per wave, barrier-free ----
#pragma unroll
    for (int i = 0; i < 4; ++i) {
        int rt = ws + 8 * i;               // 0..31 within rowgroup
        int tile64 = rg * 16 + (rt >> 1);
        int mi = rt & 1;
        const char* Ab = (const char*)h1g + (size_t)(b * 128 + tile64) * 65536 +
                         mi * 1024 + (size_t)lane * 16;

        bf16x8 pa[2], pb[2][2];
        pa[0] = *(const bf16x8*)(Ab);
        pa[1] = *(const bf16x8*)(Ab + 2048);
#pragma unroll
        for (int s = 0; s < 2; ++s)
#pragma unroll
            for (int ni = 0; ni < 2; ++ni)
                pb[s][ni] = *(const bf16x8*)(ldsB + ((s * 2 + ni) * 64 + lane) * 16);

        f32x16 acc[2] = {};
#pragma unroll
        for (int ks = 0; ks < 32; ++ks) {
            const int p = ks & 1;
            bf16x8 a0 = pa[p];
            bf16x8 b0 = pb[p][0], b1r = pb[p][1];
            if (ks < 30) {
                pa[p] = *(const bf16x8*)(Ab + (ks + 2) * 2048);
#pragma unroll
                for (int ni = 0; ni < 2; ++ni)
                    pb[p][ni] = *(const bf16x8*)(ldsB + (((ks + 2) * 2 + ni) * 64 + lane) * 16);
            }
            acc[0] = __builtin_amdgcn_mfma_f32_32x32x16_bf16(a0, b0,  acc[0], 0, 0, 0);
            acc[1] = __builtin_amdgcn_mfma_f32_32x32x16_bf16(a0, b1r, acc[1], 0, 0, 0);
        }

        // fold + reduce over 32 cols + atomic add (8 col-slices per row)
        int rowbase = tile64 * 64 + mi * 32;
#pragma unroll
        for (int r = 0; r < 16; ++r) {
            float v = fmaxf(acc[0][r] + b2v[0], 0.f) * w3v[0] +
                      fmaxf(acc[1][r] + b2v[1], 0.f) * w3v[1];
            v += __shfl_xor(v, 1, 64);
            v += __shfl_xor(v, 2, 64);
            v += __shfl_xor(v, 4, 64);
            v += __shfl_xor(v, 8, 64);
            v += __shfl_xor(v, 16, 64);
            if (l31 == 0) {
                int row = rowbase + (r & 3) + 8 * (r >> 2) + 4 * lh;
                atomicAdd(out + (size_t)row * BB + b, v);
            }
        }
    }
}

extern "C" void kernel_launch(void* const* d_in, const int* in_sizes, int n_in,
                              void* d_out, int out_size, void* d_ws, size_t ws_size,
                              hipStream_t stream) {
    const float* x  = (const float*)d_in[0];
    const float* w1 = (const float*)d_in[1];
    const float* b1 = (const float*)d_in[2];
    const float* w2 = (const float*)d_in[3];
    const float* b2 = (const float*)d_in[4];
    const float* w3 = (const float*)d_in[5];
    const float* b3 = (const float*)d_in[6];
    float* out = (float*)d_out;

    u16* w1f = (u16*)d_ws;                              // 1 MB
    u16* w2f = w1f + (size_t)BB * 8192 * 8;             // 4 MB
    u16* h1g = w2f + (size_t)BB * 32768 * 8;            // 64 MB (frag-major h1)

    prep_w<<<1280, 256, 0, stream>>>(w1, w2, w1f, w2f);
    init_out<<<(T_TEST * BB) / 256, 256, 0, stream>>>(b3, out);
    l1_kernel<<<dim3(BB, T_TEST / 64), 512, 0, stream>>>(x, w1f, b1, h1g);
    // grid.x = b*8+rg (all 8 col-slices of (b,rg) share an XCD), grid.y = nsl
    l23_kernel<<<dim3(64, 8), 512, 0, stream>>>(h1g, w2f, b2, w3, out);
}